// Round 5
// baseline (328.724 us; speedup 1.0000x reference)
//
#include <hip/hip_runtime.h>
#include <hip/hip_bf16.h>
#include <stdint.h>

typedef __bf16 bf16;
typedef __attribute__((ext_vector_type(8))) __bf16 bf16x8;
typedef __attribute__((ext_vector_type(4))) float f32x4;

#define KREAL 784
#define NTILES 26            // 25 real k-tiles of 32 + 1 zero pad tile
#define TROW   40            // row length in elements within a k-tile (32 + 8 pad)
#define TILE_ELEMS (256 * TROW)   // 10240 elements = 20 KB per k-tile
#define NPER   13            // periods; each covers 2 k-tiles (BK=64)

#define GLOBAL_AS __attribute__((address_space(1)))
#define LDS_AS    __attribute__((address_space(3)))

// ---------------------------------------------------------------------------
// Prep: fold 3x3 VALID cross-correlation into w1, emit k-tiled, row-padded:
//   W[tile][n][kk], kk in [0,40). Tile 25 is all zeros (K pad to 832) so the
//   GEMM's period loop needs no tail special-case. 80 B row stride keeps the
//   ds_read_b128 B-fragment reads at 2-lanes/bank (free, m136).
// ---------------------------------------------------------------------------
__global__ __launch_bounds__(256) void prep_w1tt(const float* __restrict__ w_conv,
                                                 const float* __restrict__ w1,
                                                 bf16* __restrict__ W) {
    const int tile = blockIdx.x / TROW;
    const int kk   = blockIdx.x % TROW;
    const int n    = threadIdx.x;
    const int k    = tile * 32 + kk;
    float s = 0.0f;
    if (kk < 32 && k < KREAL) {
        const int r = k / 28, c = k % 28;
        #pragma unroll
        for (int di = 0; di < 3; ++di) {
            const int i = r - di;
            if (i < 0 || i >= 26) continue;
            #pragma unroll
            for (int dj = 0; dj < 3; ++dj) {
                const int j = c - dj;
                if (j < 0 || j >= 26) continue;
                s += w_conv[di * 3 + dj] * w1[(i * 26 + j) * 256 + n];
            }
        }
    }
    W[(size_t)tile * TILE_ELEMS + n * TROW + kk] = (bf16)s;
}

// ---------------------------------------------------------------------------
// Fused: out = relu(x @ W1' + b1) @ w2 + b2
// M=128/block, N=256 (full), period BK=64 (2 k-subtiles of 32):
//   A: global -> regs, 256 B contiguous per row per period (DRAM-granularity
//      fix; issued before the DMA so the HBM stream leads)
//   B: global_load_lds DMA of both subtiles into single-buffered Ws (40 KB);
//      2 barriers/period, 13 periods. W is L2-resident (532 KB).
// Epilogue: 256->10 on fp32 VALU with a 16-lane shfl_xor butterfly.
// ---------------------------------------------------------------------------
__global__ __launch_bounds__(256, 2) void fused_mlp(
    const float* __restrict__ x,    // (65536, 784)
    const bf16*  __restrict__ W,    // k-tiled padded W1' (26*10240 bf16)
    const float* __restrict__ b1,   // (256)
    const float* __restrict__ w2,   // (256, 10)
    const float* __restrict__ b2,   // (10)
    float* __restrict__ out)        // (65536, 10)
{
    __shared__ bf16  Ws[2 * TILE_ELEMS];  // 40 KB (one BK=64 period)
    __shared__ float w2s[256][10];        // 10 KB
    __shared__ float b1s[256];
    __shared__ float b2s[10];

    const int t    = threadIdx.x;
    const int wave = t >> 6;
    const int lane = t & 63;
    const int c    = lane & 15;   // MFMA col / A-row within 16-tile
    const int q    = lane >> 4;   // MFMA quad (k-chunk selector)

    const int row0 = blockIdx.x * 128;

    // one-time stage of epilogue constants (first loop barrier publishes)
    for (int i = t; i < 2560; i += 256) ((float*)w2s)[i] = w2[i];
    b1s[t] = b1[t];
    if (t < 10) b2s[t] = b2[t];

    // A: lane (c,q) owns rows (wave*32 + c) and (+16), k-chunk q*8..q*8+7
    const float* arow0 = x + (size_t)(row0 + wave * 32 + c) * KREAL + q * 8;
    const float* arow1 = arow0 + (size_t)16 * KREAL;
    // B DMA: wave w, instr j stages 1 KB at offset (w*10+j) KB of the period
    const bf16* bsrc = W + (size_t)wave * 10 * 512 + lane * 8;
    char* bdst = (char*)&Ws[0] + wave * 10 * 1024;

    f32x4 acc[2][16];
    #pragma unroll
    for (int mt = 0; mt < 2; ++mt)
        #pragma unroll
        for (int nt = 0; nt < 16; ++nt)
            acc[mt][nt] = (f32x4){0.f, 0.f, 0.f, 0.f};

    #pragma unroll 1
    for (int p = 0; p < NPER; ++p) {
        const int k0 = p * 64;

        __syncthreads();   // previous period's Ws reads complete

        // ---- A: 256 B/row contiguous, issued first (HBM latency) ----
        float4 s0r0a, s0r0b, s0r1a, s0r1b, s1r0a, s1r0b, s1r1a, s1r1b;
        if (k0 + q * 8 < KREAL) {           // subtile 0 (784 % 8 == 0)
            const float* p0 = arow0 + k0;
            const float* p1 = arow1 + k0;
            s0r0a = *(const float4*)p0; s0r0b = *(const float4*)(p0 + 4);
            s0r1a = *(const float4*)p1; s0r1b = *(const float4*)(p1 + 4);
        } else {
            s0r0a = s0r0b = s0r1a = s0r1b = (float4){0.f, 0.f, 0.f, 0.f};
        }
        if (k0 + 32 + q * 8 < KREAL) {      // subtile 1
            const float* p0 = arow0 + k0 + 32;
            const float* p1 = arow1 + k0 + 32;
            s1r0a = *(const float4*)p0; s1r0b = *(const float4*)(p0 + 4);
            s1r1a = *(const float4*)p1; s1r1b = *(const float4*)(p1 + 4);
        } else {
            s1r0a = s1r0b = s1r1a = s1r1b = (float4){0.f, 0.f, 0.f, 0.f};
        }

        // ---- B: DMA both subtiles (40 KB total, 10 x 1 KB per wave) ----
        {
            const bf16* bs = bsrc + (size_t)p * 2 * TILE_ELEMS;
            #pragma unroll
            for (int j = 0; j < 10; ++j) {
                __builtin_amdgcn_global_load_lds(
                    (const GLOBAL_AS void*)(bs + j * 512),
                    (LDS_AS void*)(bdst + j * 1024), 16, 0, 0);
            }
        }

        __syncthreads();   // vmcnt(0) drain: Ws valid, A regs landed

        // ---- convert A to bf16 fragments ----
        bf16x8 a00, a01, a10, a11;   // a{sub}{rowpair}
        a00[0] = (bf16)s0r0a.x; a00[1] = (bf16)s0r0a.y; a00[2] = (bf16)s0r0a.z; a00[3] = (bf16)s0r0a.w;
        a00[4] = (bf16)s0r0b.x; a00[5] = (bf16)s0r0b.y; a00[6] = (bf16)s0r0b.z; a00[7] = (bf16)s0r0b.w;
        a01[0] = (bf16)s0r1a.x; a01[1] = (bf16)s0r1a.y; a01[2] = (bf16)s0r1a.z; a01[3] = (bf16)s0r1a.w;
        a01[4] = (bf16)s0r1b.x; a01[5] = (bf16)s0r1b.y; a01[6] = (bf16)s0r1b.z; a01[7] = (bf16)s0r1b.w;
        a10[0] = (bf16)s1r0a.x; a10[1] = (bf16)s1r0a.y; a10[2] = (bf16)s1r0a.z; a10[3] = (bf16)s1r0a.w;
        a10[4] = (bf16)s1r0b.x; a10[5] = (bf16)s1r0b.y; a10[6] = (bf16)s1r0b.z; a10[7] = (bf16)s1r0b.w;
        a11[0] = (bf16)s1r1a.x; a11[1] = (bf16)s1r1a.y; a11[2] = (bf16)s1r1a.z; a11[3] = (bf16)s1r1a.w;
        a11[4] = (bf16)s1r1b.x; a11[5] = (bf16)s1r1b.y; a11[6] = (bf16)s1r1b.z; a11[7] = (bf16)s1r1b.w;

        // ---- MFMA: 2 subtiles x 16 n-tiles x 2 m-tiles ----
        #pragma unroll
        for (int nt = 0; nt < 16; ++nt) {
            bf16x8 b0 = *(const bf16x8*)&Ws[(nt * 16 + c) * TROW + q * 8];
            acc[0][nt] = __builtin_amdgcn_mfma_f32_16x16x32_bf16(a00, b0, acc[0][nt], 0, 0, 0);
            acc[1][nt] = __builtin_amdgcn_mfma_f32_16x16x32_bf16(a01, b0, acc[1][nt], 0, 0, 0);
        }
        #pragma unroll
        for (int nt = 0; nt < 16; ++nt) {
            bf16x8 b1f = *(const bf16x8*)&Ws[TILE_ELEMS + (nt * 16 + c) * TROW + q * 8];
            acc[0][nt] = __builtin_amdgcn_mfma_f32_16x16x32_bf16(a10, b1f, acc[0][nt], 0, 0, 0);
            acc[1][nt] = __builtin_amdgcn_mfma_f32_16x16x32_bf16(a11, b1f, acc[1][nt], 0, 0, 0);
        }
    }

    // ---- epilogue: h = relu(acc + b1); out = h @ w2 + b2 ----
    // C/D layout: col = lane&15 (= n within tile), row = q*4 + reg
    float bl[16];
    #pragma unroll
    for (int nt = 0; nt < 16; ++nt) bl[nt] = b1s[nt * 16 + c];

    #pragma unroll
    for (int mt = 0; mt < 2; ++mt)
        #pragma unroll
        for (int nt = 0; nt < 16; ++nt)
            #pragma unroll
            for (int r = 0; r < 4; ++r) {
                float v = acc[mt][nt][r] + bl[nt];
                acc[mt][nt][r] = v > 0.f ? v : 0.f;
            }

    #pragma unroll 1
    for (int j = 0; j < 10; ++j) {
        float wj[16];
        #pragma unroll
        for (int nt = 0; nt < 16; ++nt) wj[nt] = w2s[nt * 16 + c][j];
        const float b2j = b2s[j];
        #pragma unroll
        for (int mt = 0; mt < 2; ++mt)
            #pragma unroll
            for (int r = 0; r < 4; ++r) {
                float s = 0.f;
                #pragma unroll
                for (int nt = 0; nt < 16; ++nt) s += acc[mt][nt][r] * wj[nt];
                s += __shfl_xor(s, 1, 64);
                s += __shfl_xor(s, 2, 64);
                s += __shfl_xor(s, 4, 64);
                s += __shfl_xor(s, 8, 64);
                if (c == j) {
                    const int row = row0 + wave * 32 + mt * 16 + q * 4 + r;
                    out[(size_t)row * 10 + j] = s + b2j;
                }
            }
    }
}

extern "C" void kernel_launch(void* const* d_in, const int* in_sizes, int n_in,
                              void* d_out, int out_size, void* d_ws, size_t ws_size,
                              hipStream_t stream) {
    const float* x  = (const float*)d_in[0];
    const float* wc = (const float*)d_in[1];
    const float* w1 = (const float*)d_in[2];
    const float* b1 = (const float*)d_in[3];
    const float* w2 = (const float*)d_in[4];
    const float* b2 = (const float*)d_in[5];
    float* out = (float*)d_out;
    bf16* W = (bf16*)d_ws;  // 26 * 10240 * 2 B = 520 KB scratch

    prep_w1tt<<<dim3(NTILES * TROW), dim3(256), 0, stream>>>(wc, w1, W);
    fused_mlp<<<dim3(65536 / 128), dim3(256), 0, stream>>>(x, W, b1, w2, b2, out);
}